// Round 9
// baseline (4470.923 us; speedup 1.0000x reference)
//
#include <hip/hip_runtime.h>

#define TT 512
#define BB 64
#define EE 300
#define HH 1024
#define GG 4096
#define NSLOT 33   // per-round h ring; drift <= ~2 rounds, stale L2 evicted by traffic

typedef _Float16 f16x8 __attribute__((ext_vector_type(8)));
typedef float f32x4 __attribute__((ext_vector_type(4)));

// Workspace:
//   flags @0, 1 KB                         per-block ROUND flags
//   hbuf  @1024, NSLOT x 131072 B          [slot][g4][kb32][quad4][b16][j8] f16
//   mask  @off_mask, 512*64*4              [t][b]
//   xA    @off_xA, 512*20480*2             [t][g4][kb10][quad][b16][j8] f16

__device__ __forceinline__ float sigmf(float x) {
    return __fdividef(1.0f, 1.0f + __expf(-x));
}
__device__ __forceinline__ float tanhsf(float x) {
    float e = __expf(-2.0f * fabsf(x));
    float r = __fdividef(1.0f - e, 1.0f + e);
    return copysignf(r, x);
}

__global__ void mask_kernel(const int* __restrict__ seq, float* __restrict__ maskf) {
    int idx = blockIdx.x * 256 + threadIdx.x;   // 512*64
    int t = idx >> 6, b = idx & 63;
    maskf[idx] = (seq[b * TT + t] != 0) ? 1.0f : 0.0f;
}

// xA[t][g][kb][quad][b][j] = f16(emb[seq[g*16+b][t]][e]), e = kb*32+quad*8+j
__global__ __launch_bounds__(256)
void xgather_kernel(const float* __restrict__ emb, const int* __restrict__ seq,
                    _Float16* __restrict__ xA) {
    __shared__ float xrow[64 * 305];
    const int t = blockIdx.x, tid = threadIdx.x;
    const int r = tid >> 2, sub = tid & 3;
    const int row = seq[r * TT + t];
    for (int e = sub; e < EE; e += 4)
        xrow[r * 305 + e] = emb[row * EE + e];
    __syncthreads();
    unsigned int* dst = (unsigned int*)(xA + (size_t)t * 20480);
    for (int idx = tid; idx < 10240; idx += 256) {
        int el = idx << 1;
        int j = el & 7, b = (el >> 3) & 15, quad = (el >> 7) & 3, r2 = el >> 9;
        int g = r2 / 10, kb = r2 - g * 10;
        int e = (kb << 5) + (quad << 3) + j;
        int bg = (g << 4) + b;
        union { _Float16 h[2]; unsigned int u; } pk;
        pk.h[0] = (e < EE)     ? (_Float16)xrow[bg * 305 + e]     : (_Float16)0.f;
        pk.h[1] = (e + 1 < EE) ? (_Float16)xrow[bg * 305 + e + 1] : (_Float16)0.f;
        dst[idx] = pk.u;
    }
}

// Persistent LSTM, batch-group pipelined. 256 WGs x 512 thr (1/CU via ~87KB LDS).
// 4 batch-groups of 16 round-robin per round t. Wave 0 = gates/publish; waves
// 1-7 own K (kb 5,5,5,5,4,4,4) + x.W with B-frags in registers. No
// __syncthreads in the loop. r8 race fixed: per-wave progress array prog[7]
// (release/acquire) replaces the cumulative counter -- wave0 takes a true
// min over producers, so compute-wave run-ahead can no longer satisfy the
// reduce precondition while a slow wave's partial is missing.
__global__ __launch_bounds__(512, 2)
void lstm_kernel(const _Float16* __restrict__ xA, const float* __restrict__ rk,
                 const float* __restrict__ wk, const float* __restrict__ bias,
                 const float* __restrict__ maskf, _Float16* __restrict__ hbuf,
                 unsigned int* __restrict__ flags, float* __restrict__ out) {
    __shared__ _Float16 RbL[16384];  // [kb32][quad][c16][j8] B-frags of R
    __shared__ _Float16 WbL[5120];   // [kb10][quad][c16][j8] B-frags of W
    __shared__ float zb[4480];       // 2 x [112 rows][20] partials (parity = id&1)
    __shared__ float cs[256];        // [g4][uu4][b16] cell state
    __shared__ __align__(8) _Float16 hsh[64];   // [b16][uu4] publish staging
    __shared__ unsigned int prog[8]; // per-compute-wave progress (id+1); [7]=sentinel
    __shared__ unsigned int rel;     // wave0 reduce progress (id+1)
    __shared__ float padf[6200];     // occupancy forcing (~24.8KB -> 1 WG/CU)
    const int tid = threadIdx.x;
    const int lane = tid & 63;
    const int w = tid >> 6;
    const int p = blockIdx.x;
    const int p4 = p << 2;
    const int cc = lane & 15, quad = lane >> 4;

    for (int i = tid; i < 16384; i += 512) {
        int k = i >> 4, c = i & 15;
        float v = rk[k * GG + ((c >> 2) << 10) + p4 + (c & 3)];
        RbL[((k >> 5) << 9) + (((k >> 3) & 3) << 7) + (c << 3) + (k & 7)] = (_Float16)v;
    }
    for (int i = tid; i < 5120; i += 512) {
        int e = i >> 4, c = i & 15;
        float v = (e < EE) ? wk[e * GG + ((c >> 2) << 10) + p4 + (c & 3)] : 0.f;
        WbL[((e >> 5) << 9) + (((e >> 3) & 3) << 7) + (c << 3) + (e & 7)] = (_Float16)v;
    }
    if (tid < 256) cs[tid] = 0.f;
    if (tid < 8) prog[tid] = (tid == 7) ? 0xFFFFFFFFu : 0u;
    if (tid == 0) rel = 0u;
    __syncthreads();
    if ((size_t)out == 1) { padf[tid] = cs[0]; out[0] = padf[tid]; }  // keep padf

    if (w == 0) {
        // ---- gates / publish wave ----
        const int uu = lane >> 4, b = lane & 15;
        float bb0 = bias[p4 + uu], bb1 = bias[1024 + p4 + uu];
        float bb2 = bias[2048 + p4 + uu], bb3 = bias[3072 + p4 + uu];
        float hw[4] = {0.f, 0.f, 0.f, 0.f};
        const size_t puboff = ((((size_t)(p >> 3) << 2) + ((p >> 1) & 3)) << 7)
                              + ((size_t)lane << 3) + ((size_t)(p & 1) << 2);
        for (int t = 0; t < TT; ++t) {
            _Float16* hb = hbuf + (size_t)((t + 1) % NSLOT) * 65536;
#pragma unroll
            for (int g = 0; g < 4; ++g) {
                const int id = (t << 2) + g;
                // wait until EVERY compute wave has deposited its id partial
                while (!__all((int)(__hip_atomic_load(prog + (lane & 7), __ATOMIC_ACQUIRE,
                                                      __HIP_MEMORY_SCOPE_WORKGROUP)
                                    >= (unsigned)(id + 1))))
                    __builtin_amdgcn_s_sleep(0);
                __builtin_amdgcn_sched_barrier(0);
                const float* zr = zb + (id & 1) * 2240;
                float z0 = bb0, z1 = bb1, z2 = bb2, z3 = bb3;
#pragma unroll
                for (int wp = 0; wp < 7; ++wp) {
                    const float* zw = zr + (wp << 4) * 20;
                    z0 += zw[uu * 20 + b];
                    z1 += zw[(4 + uu) * 20 + b];
                    z2 += zw[(8 + uu) * 20 + b];
                    z3 += zw[(12 + uu) * 20 + b];
                }
                if (lane == 0)
                    __hip_atomic_store(&rel, (unsigned)(id + 1), __ATOMIC_RELEASE,
                                       __HIP_MEMORY_SCOPE_WORKGROUP);
                float m = maskf[(t << 6) + (g << 4) + b];
                float fi = sigmf(z0);
                float ff = sigmf(z1);
                float fg = tanhsf(z2);
                float fo = sigmf(z3);
                float co = cs[(g << 6) + lane];
                float cn = fmaf(ff, co, fi * fg);
                cn = fmaf(m, cn - co, co);
                cs[(g << 6) + lane] = cn;
                float hc = fo * tanhsf(cn);
                hw[g] = fmaf(m, hc - hw[g], hw[g]);
                hsh[(b << 2) + uu] = (_Float16)hw[g];
                if (lane < 16) {
                    unsigned long long hv = ((const unsigned long long*)hsh)[lane];
                    __hip_atomic_store((unsigned long long*)(hb + ((size_t)g << 14) + puboff),
                                       hv, __ATOMIC_RELAXED, __HIP_MEMORY_SCOPE_AGENT);
                }
            }
            __asm__ volatile("s_waitcnt vmcnt(0)" ::: "memory");  // all 64 publishes acked
            if (lane == 0)
                __hip_atomic_store(flags + p, (unsigned)(t + 1),
                                   __ATOMIC_RELAXED, __HIP_MEMORY_SCOPE_AGENT);
        }
#pragma unroll
        for (int g = 0; g < 4; ++g)
            out[(((g << 4) + b) << 10) + p4 + uu] = hw[g];
    } else {
        // ---- compute waves 1..7: K-partition + x.W ----
        const int wi = w - 1;
        const int rec0 = (wi < 4) ? wi * 5 : 20 + ((wi - 4) << 2);
        const int nrec = (wi < 4) ? 5 : 4;
        const int xw0  = (wi < 4) ? wi : 4 + ((wi - 4) << 1);
        const int nxw  = (wi < 4) ? 1 : 2;
        f16x8 bfr[5], bfx[2];
#pragma unroll
        for (int r = 0; r < 5; ++r) if (r < nrec)
            bfr[r] = *(const f16x8*)(RbL + ((rec0 + r) << 9) + (quad << 7) + (cc << 3));
#pragma unroll
        for (int xi = 0; xi < 2; ++xi) if (xi < nxw)
            bfx[xi] = *(const f16x8*)(WbL + ((xw0 + xi) << 9) + (quad << 7) + (cc << 3));
        const int nprod = nrec << 3;
        const int fl = (rec0 << 3) + ((lane < nprod) ? lane : nprod - 1);

        for (int t = 0; t < TT; ++t) {
            f32x4 acc[4];
#pragma unroll
            for (int g = 0; g < 4; ++g) acc[g] = (f32x4){0.f, 0.f, 0.f, 0.f};
            // x.W for all 4 groups: no remote dep, overlaps the flag poll
            const f16x8* xt8 = (const f16x8*)(xA + (size_t)t * 20480);
#pragma unroll
            for (int xi = 0; xi < 2; ++xi) if (xi < nxw) {
                const int kb = xw0 + xi;
#pragma unroll
                for (int g = 0; g < 4; ++g) {
                    f16x8 af = xt8[g * 640 + (kb << 6) + (quad << 4) + cc];
                    acc[g] = __builtin_amdgcn_mfma_f32_16x16x32_f16(af, bfx[xi], acc[g], 0, 0, 0);
                }
            }
            // round poll: my producers finished round t-1 (published h^t, all groups)
            unsigned tgt = (unsigned)t;
            while (!__all((int)(__hip_atomic_load(flags + fl, __ATOMIC_RELAXED,
                                                  __HIP_MEMORY_SCOPE_AGENT) >= tgt)))
                __builtin_amdgcn_s_sleep(1);
            __builtin_amdgcn_sched_barrier(0);
            const f16x8* h8 = (const f16x8*)(hbuf + (size_t)(t % NSLOT) * 65536);
#pragma unroll
            for (int g = 0; g < 4; ++g) {
                const int id = (t << 2) + g;
                if (id >= 2) {   // zb parity reuse guard: wave0 done reading id-2
                    while (__hip_atomic_load(&rel, __ATOMIC_ACQUIRE,
                                             __HIP_MEMORY_SCOPE_WORKGROUP) < (unsigned)(id - 1))
                        __builtin_amdgcn_s_sleep(0);
                }
                __builtin_amdgcn_sched_barrier(0);
                const f16x8* hg = h8 + ((size_t)g << 11);
#pragma unroll
                for (int r = 0; r < 5; ++r) if (r < nrec) {
                    const int kb = rec0 + r;
                    f16x8 af = hg[(kb << 6) + (quad << 4) + cc];
                    acc[g] = __builtin_amdgcn_mfma_f32_16x16x32_f16(af, bfr[r], acc[g], 0, 0, 0);
                }
                *(f32x4*)(zb + (id & 1) * 2240 + ((wi << 4) + cc) * 20 + (quad << 2)) = acc[g];
                if (lane == 0)
                    __hip_atomic_store(prog + wi, (unsigned)(id + 1), __ATOMIC_RELEASE,
                                       __HIP_MEMORY_SCOPE_WORKGROUP);
            }
        }
    }
}

extern "C" void kernel_launch(void* const* d_in, const int* in_sizes, int n_in,
                              void* d_out, int out_size, void* d_ws, size_t ws_size,
                              hipStream_t stream) {
    const float* emb  = (const float*)d_in[0];
    const float* wk   = (const float*)d_in[1];
    const float* rk   = (const float*)d_in[2];
    const float* bias = (const float*)d_in[3];
    const int*   seq  = (const int*)d_in[4];
    float* out = (float*)d_out;
    char* ws = (char*)d_ws;

    const size_t off_hbuf = 1024;
    const size_t off_mask = off_hbuf + (size_t)NSLOT * 131072;
    const size_t off_xA   = off_mask + 131072;
    unsigned int* flags = (unsigned int*)ws;
    _Float16* hbuf  = (_Float16*)(ws + off_hbuf);
    float*    maskf = (float*)(ws + off_mask);
    _Float16* xA    = (_Float16*)(ws + off_xA);

    // zero flags + hbuf slot 0 (all 4 groups; contiguous prefix)
    hipMemsetAsync(ws, 0, off_hbuf + 131072, stream);
    mask_kernel<<<128, 256, 0, stream>>>(seq, maskf);
    xgather_kernel<<<TT, 256, 0, stream>>>(emb, seq, xA);
    lstm_kernel<<<256, 512, 0, stream>>>(xA, rk, wk, bias, maskf, hbuf, flags, out);
}

// Round 10
// 2634.111 us; speedup vs baseline: 1.6973x; 1.6973x over previous
//
#include <hip/hip_runtime.h>

#define TT 512
#define BB 64
#define EE 300
#define HH 1024
#define GG 4096
#define NSLOT 33   // h ring; skew bounded ~1 round by the per-round flag barrier

typedef _Float16 f16x8 __attribute__((ext_vector_type(8)));
typedef float f32x4 __attribute__((ext_vector_type(4)));

// Workspace:
//   flags @0, 4 KB            flags[g][p]: per-(group,block) round counters
//   hbuf  @4096, NSLOT x 131072 B   [slot][g4][kb32][quad4][b16][j8] f16
//   mask  @off_mask, 512*64*4       [t][b]
//   xA    @off_xA, 512*20480*2      [t][g4][kb10][quad][b16][j8] f16

__device__ __forceinline__ float sigmf(float x) {
    return __fdividef(1.0f, 1.0f + __expf(-x));
}
__device__ __forceinline__ float tanhsf(float x) {
    float e = __expf(-2.0f * fabsf(x));
    float r = __fdividef(1.0f - e, 1.0f + e);
    return copysignf(r, x);
}

__global__ void mask_kernel(const int* __restrict__ seq, float* __restrict__ maskf) {
    int idx = blockIdx.x * 256 + threadIdx.x;   // 512*64
    int t = idx >> 6, b = idx & 63;
    maskf[idx] = (seq[b * TT + t] != 0) ? 1.0f : 0.0f;
}

// xA[t][g][kb][quad][b][j] = f16(emb[seq[g*16+b][t]][e]), e = kb*32+quad*8+j
__global__ __launch_bounds__(256)
void xgather_kernel(const float* __restrict__ emb, const int* __restrict__ seq,
                    _Float16* __restrict__ xA) {
    __shared__ float xrow[64 * 305];
    const int t = blockIdx.x, tid = threadIdx.x;
    const int r = tid >> 2, sub = tid & 3;
    const int row = seq[r * TT + t];
    for (int e = sub; e < EE; e += 4)
        xrow[r * 305 + e] = emb[row * EE + e];
    __syncthreads();
    unsigned int* dst = (unsigned int*)(xA + (size_t)t * 20480);
    for (int idx = tid; idx < 10240; idx += 256) {
        int el = idx << 1;
        int j = el & 7, b = (el >> 3) & 15, quad = (el >> 7) & 3, r2 = el >> 9;
        int g = r2 / 10, kb = r2 - g * 10;
        int e = (kb << 5) + (quad << 3) + j;
        int bg = (g << 4) + b;
        union { _Float16 h[2]; unsigned int u; } pk;
        pk.h[0] = (e < EE)     ? (_Float16)xrow[bg * 305 + e]     : (_Float16)0.f;
        pk.h[1] = (e + 1 < EE) ? (_Float16)xrow[bg * 305 + e + 1] : (_Float16)0.f;
        dst[idx] = pk.u;
    }
}

// Persistent LSTM: 256 WGs x 256 thr (4 waves, 1/SIMD; 1 WG/CU via ~110KB LDS).
// Wave g owns batch-group g COMPLETELY: full-K MFMA (32 R + 10 W chunks, all
// B-frags in registers), gates, c/h state in registers, per-wave LDS scratch
// for the C-layout transpose, per-wave publish + per-(group,block) flag.
// NO __syncthreads / cross-wave handshake in the loop (r9 post-mortem: LDS
// producer-consumer ping-pong ~ as expensive as global sync). 4 acc chains
// hide MFMA dep latency at 1 wave/SIMD; 8-deep h prefetch ring (r7-proven).
__global__ __launch_bounds__(256, 1)
void lstm_kernel(const _Float16* __restrict__ xA, const float* __restrict__ rk,
                 const float* __restrict__ wk, const float* __restrict__ bias,
                 const float* __restrict__ maskf, _Float16* __restrict__ hbuf,
                 unsigned int* __restrict__ flags, float* __restrict__ out) {
    __shared__ _Float16 RbL[16384];        // staging: [kb32][quad][c16][j8]
    __shared__ _Float16 WbL[5120];         // staging: [kb10][quad][c16][j8]
    __shared__ float zsc[4][272];          // per-wave transpose scratch (stride 17)
    __shared__ __align__(8) _Float16 zh[4][64];   // per-wave publish staging [b][u]
    __shared__ float padf[16000];          // 64KB occupancy pad (volatile-kept)
    const int tid = threadIdx.x;
    const int lane = tid & 63;
    const int g = tid >> 6;                // wave index == batch group
    const int p = blockIdx.x;
    const int p4 = p << 2;
    const int cc = lane & 15, quad = lane >> 4;

    ((volatile float*)padf)[tid] = 0.f;    // defeat LDS DCE (r9: pad was eliminated)

    // stage B-fragments of R (k x 16 cols) and W, f16, once
    for (int i = tid; i < 16384; i += 256) {
        int k = i >> 4, c = i & 15;
        float v = rk[k * GG + ((c >> 2) << 10) + p4 + (c & 3)];
        RbL[((k >> 5) << 9) + (((k >> 3) & 3) << 7) + (c << 3) + (k & 7)] = (_Float16)v;
    }
    for (int i = tid; i < 5120; i += 256) {
        int e = i >> 4, c = i & 15;
        float v = (e < EE) ? wk[e * GG + ((c >> 2) << 10) + p4 + (c & 3)] : 0.f;
        WbL[((e >> 5) << 9) + (((e >> 3) & 3) << 7) + (c << 3) + (e & 7)] = (_Float16)v;
    }
    __syncthreads();   // prologue only

    f16x8 bR[32], bW[10];
#pragma unroll
    for (int kb = 0; kb < 32; ++kb)
        bR[kb] = *(const f16x8*)(RbL + (kb << 9) + (quad << 7) + (cc << 3));
#pragma unroll
    for (int kb = 0; kb < 10; ++kb)
        bW[kb] = *(const f16x8*)(WbL + (kb << 9) + (quad << 7) + (cc << 3));

    const float bb0 = bias[p4 + quad];
    const float bb1 = bias[1024 + p4 + quad];
    const float bb2 = bias[2048 + p4 + quad];
    const float bb3 = bias[3072 + p4 + quad];
    float c_st = 0.f, hw = 0.f;            // cell & hidden state: 1 reg each/lane
    int slot = 0, nslot = 1;
    const unsigned int* fg = flags + (g << 8);
    // publish address (ull units): see layout derivation; k = 4p+u
    const size_t pub_base = ((size_t)(p >> 3) << 7) + ((size_t)((p >> 1) & 3) << 5) +
                            ((size_t)lane << 1) + (size_t)(p & 1) + ((size_t)g << 12);

    for (int t = 0; t < TT; ++t) {
        f32x4 acc[4];
#pragma unroll
        for (int i = 0; i < 4; ++i) acc[i] = (f32x4){0.f, 0.f, 0.f, 0.f};

        // ---- x.W (no remote dep): overlaps the flag poll below ----
        const f16x8* xt8 = (const f16x8*)(xA + (size_t)t * 20480) + g * 640;
#pragma unroll
        for (int kb = 0; kb < 10; ++kb) {
            f16x8 af = xt8[(kb << 6) + (quad << 4) + cc];
            acc[kb & 3] = __builtin_amdgcn_mfma_f32_16x16x32_f16(af, bW[kb], acc[kb & 3], 0, 0, 0);
        }
        float m = maskf[(t << 6) + (g << 4) + cc];

        // ---- poll my group's 256 producer flags (4 coalesced atomic loads) ----
        {
            unsigned tgt = (unsigned)t;
            for (;;) {
                unsigned f0 = __hip_atomic_load(fg + lane,       __ATOMIC_RELAXED, __HIP_MEMORY_SCOPE_AGENT);
                unsigned f1 = __hip_atomic_load(fg + 64 + lane,  __ATOMIC_RELAXED, __HIP_MEMORY_SCOPE_AGENT);
                unsigned f2 = __hip_atomic_load(fg + 128 + lane, __ATOMIC_RELAXED, __HIP_MEMORY_SCOPE_AGENT);
                unsigned f3 = __hip_atomic_load(fg + 192 + lane, __ATOMIC_RELAXED, __HIP_MEMORY_SCOPE_AGENT);
                unsigned mn = min(min(f0, f1), min(f2, f3));
                if (__all((int)(mn >= tgt))) break;
                __builtin_amdgcn_s_sleep(1);
            }
        }
        __builtin_amdgcn_sched_barrier(0);

        // ---- h.R: full K, 8-deep prefetch ring, 4 acc chains ----
        const f16x8* hp8 = (const f16x8*)hbuf + (size_t)slot * 8192 + ((size_t)g << 11);
        f16x8 hv[8];
#pragma unroll
        for (int i = 0; i < 8; ++i) hv[i] = hp8[(i << 6) + (quad << 4) + cc];
#pragma unroll
        for (int g8 = 0; g8 < 4; ++g8) {
#pragma unroll
            for (int j = 0; j < 8; ++j) {
                f16x8 cur = hv[j];
                const int kb = (g8 << 3) + j;
                if (g8 < 3) hv[j] = hp8[((kb + 8) << 6) + (quad << 4) + cc];
                acc[kb & 3] = __builtin_amdgcn_mfma_f32_16x16x32_f16(cur, bR[kb], acc[kb & 3], 0, 0, 0);
            }
        }
        f32x4 s = (acc[0] + acc[1]) + (acc[2] + acc[3]);

        // ---- per-wave transpose (C: col=cc, row=quad*4+i) + gates ----
#pragma unroll
        for (int i = 0; i < 4; ++i)
            zsc[g][((quad << 2) + i) * 17 + cc] = s[i];
        // compiler inserts lgkmcnt(0); same-wave DS FIFO, no barrier needed
        float z0 = zsc[g][cc * 17 + quad]      + bb0;
        float z1 = zsc[g][cc * 17 + 4 + quad]  + bb1;
        float z2 = zsc[g][cc * 17 + 8 + quad]  + bb2;
        float z3 = zsc[g][cc * 17 + 12 + quad] + bb3;
        float fi = sigmf(z0);
        float ff = sigmf(z1);
        float fgv = tanhsf(z2);
        float fo = sigmf(z3);
        float cn = fmaf(ff, c_st, fi * fgv);
        cn = fmaf(m, cn - c_st, c_st);         // masked c update
        c_st = cn;
        float hc = fo * tanhsf(cn);
        hw = fmaf(m, hc - hw, hw);             // masked h update (f32 state)
        zh[g][(cc << 2) + quad] = (_Float16)hw;
        // ---- publish (16 lanes x 8B) + per-wave ack + flag ----
        if (lane < 16) {
            unsigned long long hv8 = ((const unsigned long long*)(&zh[g][0]))[lane];
            __hip_atomic_store((unsigned long long*)hbuf + (size_t)nslot * 16384 + pub_base,
                               hv8, __ATOMIC_RELAXED, __HIP_MEMORY_SCOPE_AGENT);
        }
        __asm__ volatile("s_waitcnt vmcnt(0)" ::: "memory");   // this wave's stores acked
        if (lane == 0)
            __hip_atomic_store(flags + (g << 8) + p, (unsigned)(t + 1),
                               __ATOMIC_RELAXED, __HIP_MEMORY_SCOPE_AGENT);
        slot = nslot;
        nslot = (nslot + 1 == NSLOT) ? 0 : nslot + 1;
    }
    // final h -> out: lane (u=quad, b=cc) of wave g
    out[(((g << 4) + cc) << 10) + p4 + quad] = hw;
}

extern "C" void kernel_launch(void* const* d_in, const int* in_sizes, int n_in,
                              void* d_out, int out_size, void* d_ws, size_t ws_size,
                              hipStream_t stream) {
    const float* emb  = (const float*)d_in[0];
    const float* wk   = (const float*)d_in[1];
    const float* rk   = (const float*)d_in[2];
    const float* bias = (const float*)d_in[3];
    const int*   seq  = (const int*)d_in[4];
    float* out = (float*)d_out;
    char* ws = (char*)d_ws;

    const size_t off_hbuf = 4096;
    const size_t off_mask = off_hbuf + (size_t)NSLOT * 131072;
    const size_t off_xA   = off_mask + 131072;
    unsigned int* flags = (unsigned int*)ws;
    _Float16* hbuf  = (_Float16*)(ws + off_hbuf);
    float*    maskf = (float*)(ws + off_mask);
    _Float16* xA    = (_Float16*)(ws + off_xA);

    // zero flags (4KB) + hbuf slot 0 (contiguous prefix)
    hipMemsetAsync(ws, 0, off_hbuf + 131072, stream);
    mask_kernel<<<128, 256, 0, stream>>>(seq, maskf);
    xgather_kernel<<<TT, 256, 0, stream>>>(emb, seq, xA);
    lstm_kernel<<<256, 256, 0, stream>>>(xA, rk, wk, bias, maskf, hbuf, flags, out);
}